// Round 4
// baseline (1178.566 us; speedup 1.0000x reference)
//
#include <hip/hip_runtime.h>
#include <hip/hip_bf16.h>

#define NN 8192     // total nodes
#define CC 256      // nodes per graph == in_channels
#define BBg 32      // graphs
#define HH 128      // hidden
#define EE 131072   // edges

typedef __attribute__((ext_vector_type(8))) short short8;
typedef __attribute__((ext_vector_type(4))) float f32x4;
typedef unsigned long long ull;

// Replicate fp32 hard_where(sigmoid(v)) boundary exactly (see round-0 notes).
__device__ __forceinline__ float hard01(float v) {
    if (v >= 1e-6f) return 1.0f;
    if (v <= 0.0f) return 0.0f;
    float ef = (float)exp(-(double)v);
    float s = 1.0f / (1.0f + ef);
    return (s > 0.5f) ? 1.0f : 0.0f;
}

__device__ __forceinline__ unsigned short f2bf(float f) {
    unsigned u = __float_as_uint(f);
    u += 0x7FFFu + ((u >> 16) & 1u);   // RNE
    return (unsigned short)(u >> 16);
}
__device__ __forceinline__ float bf2f(unsigned short b) {
    return __uint_as_float(((unsigned)b) << 16);
}

// ---- D2: hist (blocks 0..511) + mask (blocks 512..2559) -----------------
__global__ void k_hist_mask(const int* __restrict__ ei, int* __restrict__ rowcnt,
                            int* __restrict__ colcnt, unsigned char* __restrict__ coljs,
                            const float* __restrict__ maskW, const int* __restrict__ gid,
                            const float* __restrict__ x, float* __restrict__ Mo,
                            float* __restrict__ xm) {
    int blk = blockIdx.x, t = threadIdx.x;
    if (blk < 512) {
        int e = blk * 256 + t;
        int r = ei[e], c = ei[EE + e];
        atomicAdd(&rowcnt[r], 1);
        int idx = (r >> 8) * NN + c;
        int slot = atomicAdd(&colcnt[idx], 1);
        if (slot < 16) coljs[(size_t)idx * 16 + slot] = (unsigned char)(r & 255);
    } else {
        int i = (blk - 512) * 256 + t;
        int base = i * 4;
        int r = base >> 8;
        int c = base & 255;
        int g = gid[r >> 8];
        float4 mv = *(const float4*)(maskW + ((size_t)g << 16) + ((size_t)(r & 255) << 8) + c);
        float4 xv = *(const float4*)(x + ((size_t)r << 8) + c);
        float4 m, o;
        m.x = hard01(mv.x); m.y = hard01(mv.y); m.z = hard01(mv.z); m.w = hard01(mv.w);
        o.x = m.x * xv.x; o.y = m.y * xv.y; o.z = m.z * xv.z; o.w = m.w * xv.w;
        *(float4*)(Mo + ((size_t)r << 8) + c) = m;
        *(float4*)(xm + ((size_t)r << 8) + c) = o;
    }
}

// ---- D3: scan (block 0) + pertadj (blocks 1..1024) ----------------------
__global__ void __launch_bounds__(256) k_scan_pertadj(
        const int* __restrict__ rowcnt, int* __restrict__ rowptr,
        int* __restrict__ rowfill,
        const float* __restrict__ pertW, const float* __restrict__ pertB,
        const int* __restrict__ gid, const int* __restrict__ colcnt,
        const unsigned char* __restrict__ coljs,
        float* __restrict__ padj, unsigned char* __restrict__ padjbits) {
    __shared__ float Pl[32][257];
    __shared__ int sums[256];
    int t = threadIdx.x;
    if (blockIdx.x == 0) {
        int base = t * 32;
        int loc[32];
        int s = 0;
        #pragma unroll
        for (int i = 0; i < 32; ++i) { loc[i] = s; s += rowcnt[base + i]; }
        sums[t] = s;
        __syncthreads();
        if (t == 0) {
            int a = 0;
            for (int i = 0; i < 256; ++i) { int v = sums[i]; sums[i] = a; a += v; }
            rowptr[NN] = a;
        }
        __syncthreads();
        int off = sums[t];
        #pragma unroll
        for (int i = 0; i < 32; ++i) {
            rowptr[base + i] = off + loc[i];
            rowfill[base + i] = off + loc[i];
        }
        return;
    }
    int bid = blockIdx.x - 1;
    int nc = bid & 3, rt = (bid >> 2) & 7, b = bid >> 5;
    int g = gid[b];
    const float* src = pertW + ((size_t)g << 16) + (size_t)rt * 32 * CC;
    #pragma unroll 4
    for (int i = 0; i < 32; ++i) Pl[i][t] = src[i * CC + t];
    __syncthreads();
    int ty = t >> 6, tx = t & 63;          // ty: 8-row group; tx: 8-col group
    int ro = ty * 8;
    const float* bsrc = pertB + ((size_t)g << 16) + (size_t)(rt * 32 + ro) * CC;
    for (int it = 0; it < 4; ++it) {
        unsigned bits[8];
        #pragma unroll
        for (int ii = 0; ii < 8; ++ii) bits[ii] = 0;
        #pragma unroll
        for (int half = 0; half < 2; ++half) {
            int n = nc * 2048 + it * 512 + tx * 8 + half * 4;
            int cidx = b * NN + n;
            int4 cnt4 = *(const int4*)(colcnt + cidx);
            const uint4* jp = (const uint4*)(coljs + (size_t)cidx * 16);
            float s[8][4];
            #pragma unroll
            for (int ii = 0; ii < 8; ++ii)
                #pragma unroll
                for (int cc = 0; cc < 4; ++cc) s[ii][cc] = 0.0f;
            #pragma unroll
            for (int cc = 0; cc < 4; ++cc) {
                int cnt = (&cnt4.x)[cc];
                cnt = cnt > 16 ? 16 : cnt;
                if (cnt == 0) continue;
                uint4 jv = jp[cc];
                for (int q = 0; q < cnt; ++q) {
                    unsigned word = (q < 8) ? ((q < 4) ? jv.x : jv.y)
                                            : ((q < 12) ? jv.z : jv.w);
                    int j = (word >> ((q & 3) * 8)) & 255;
                    #pragma unroll
                    for (int ii = 0; ii < 8; ++ii) s[ii][cc] += Pl[ro + ii][j];
                }
            }
            bool diag = ((n >> 8) == b);
            #pragma unroll
            for (int ii = 0; ii < 8; ++ii) {
                float4 v = make_float4(s[ii][0], s[ii][1], s[ii][2], s[ii][3]);
                if (diag) {
                    float4 bv = *(const float4*)(bsrc + (size_t)ii * CC + (n & 255));
                    v.x += bv.x; v.y += bv.y; v.z += bv.z; v.w += bv.w;
                }
                float4 f;
                f.x = hard01(v.x); f.y = hard01(v.y); f.z = hard01(v.z); f.w = hard01(v.w);
                size_t ob = (size_t)(b * CC + rt * 32 + ro + ii) * NN + n;
                *(float4*)(padj + ob) = f;
                unsigned nib = (f.x != 0.f ? 1u : 0u) | (f.y != 0.f ? 2u : 0u) |
                               (f.z != 0.f ? 4u : 0u) | (f.w != 0.f ? 8u : 0u);
                bits[ii] |= nib << (half * 4);
            }
        }
        #pragma unroll
        for (int ii = 0; ii < 8; ++ii) {
            size_t bb = (size_t)(b * CC + rt * 32 + ro + ii) * (NN / 8)
                        + nc * 256 + it * 64 + tx;
            padjbits[bb] = (unsigned char)bits[ii];
        }
    }
}

// ---- gemm_dual body (used by D4/D6/D8) ----------------------------------
__device__ __forceinline__ void gemm_dual_body(
        int mt, int t,
        const float* __restrict__ Ap, const float* __restrict__ Aa,
        const float* __restrict__ W, float* __restrict__ Zp,
        unsigned short* __restrict__ Zthi, unsigned short* __restrict__ Ztlo,
        int K, int relu, int aparts, int apstride,
        float (*Alp)[68], float (*Ala)[68], float (*Wl)[132]) {
    int ty = t >> 3, tx = t & 7;
    float accp[16], acca[16];
    #pragma unroll
    for (int u = 0; u < 16; ++u) { accp[u] = 0.0f; acca[u] = 0.0f; }
    for (int kc = 0; kc < K; kc += 64) {
        int row = t >> 3, q = t & 7;
        {
            const float* ap = Ap + (size_t)(mt * 32 + row) * K + kc + q * 8;
            float4 f0 = *(const float4*)ap;
            float4 f1 = *(const float4*)(ap + 4);
            if (relu) {
                f0.x = fmaxf(f0.x, 0.f); f0.y = fmaxf(f0.y, 0.f);
                f0.z = fmaxf(f0.z, 0.f); f0.w = fmaxf(f0.w, 0.f);
                f1.x = fmaxf(f1.x, 0.f); f1.y = fmaxf(f1.y, 0.f);
                f1.z = fmaxf(f1.z, 0.f); f1.w = fmaxf(f1.w, 0.f);
            }
            *(float4*)&Alp[row][q * 8] = f0;
            *(float4*)&Alp[row][q * 8 + 4] = f1;
        }
        {
            const float* ap = Aa + (size_t)(mt * 32 + row) * K + kc + q * 8;
            float4 f0 = *(const float4*)ap;
            float4 f1 = *(const float4*)(ap + 4);
            for (int p = 1; p < aparts; ++p) {
                float4 g0 = *(const float4*)(ap + (size_t)p * apstride);
                float4 g1 = *(const float4*)(ap + (size_t)p * apstride + 4);
                f0.x += g0.x; f0.y += g0.y; f0.z += g0.z; f0.w += g0.w;
                f1.x += g1.x; f1.y += g1.y; f1.z += g1.z; f1.w += g1.w;
            }
            if (relu) {
                f0.x = fmaxf(f0.x, 0.f); f0.y = fmaxf(f0.y, 0.f);
                f0.z = fmaxf(f0.z, 0.f); f0.w = fmaxf(f0.w, 0.f);
                f1.x = fmaxf(f1.x, 0.f); f1.y = fmaxf(f1.y, 0.f);
                f1.z = fmaxf(f1.z, 0.f); f1.w = fmaxf(f1.w, 0.f);
            }
            *(float4*)&Ala[row][q * 8] = f0;
            *(float4*)&Ala[row][q * 8 + 4] = f1;
        }
        {
            int wrow = t >> 2, wq = t & 3;
            const float* wp = W + (size_t)(kc + wrow) * HH + wq * 32;
            #pragma unroll
            for (int u = 0; u < 32; u += 4)
                *(float4*)&Wl[wrow][wq * 32 + u] = *(const float4*)(wp + u);
        }
        __syncthreads();
        #pragma unroll 2
        for (int kk = 0; kk < 64; ++kk) {
            float a = Alp[ty][kk];
            float b2 = Ala[ty][kk];
            #pragma unroll
            for (int u = 0; u < 16; u += 4) {
                float4 wv = *(const float4*)(&Wl[kk][tx * 16 + u]);
                accp[u + 0] += a * wv.x; accp[u + 1] += a * wv.y;
                accp[u + 2] += a * wv.z; accp[u + 3] += a * wv.w;
                acca[u + 0] += b2 * wv.x; acca[u + 1] += b2 * wv.y;
                acca[u + 2] += b2 * wv.z; acca[u + 3] += b2 * wv.w;
            }
        }
        __syncthreads();
    }
    {
        float* cp = Zp + (size_t)(mt * 32 + ty) * HH + tx * 16;
        #pragma unroll
        for (int u = 0; u < 16; u += 4) {
            float4 f;
            f.x = accp[u]; f.y = accp[u + 1]; f.z = accp[u + 2]; f.w = accp[u + 3];
            *(float4*)(cp + u) = f;
        }
    }
    {
        __syncthreads();
        float* Tl = &Wl[0][0];  // reuse as [32][132]
        #pragma unroll
        for (int u = 0; u < 16; ++u) Tl[ty * 132 + tx * 16 + u] = acca[u];
        __syncthreads();
        int col = t >> 1, half = t & 1;
        unsigned short hu[16] __attribute__((aligned(16)));
        unsigned short lu[16] __attribute__((aligned(16)));
        #pragma unroll
        for (int rr = 0; rr < 16; ++rr) {
            float v = Tl[(half * 16 + rr) * 132 + col];
            unsigned short hb = f2bf(v);
            hu[rr] = hb;
            lu[rr] = f2bf(v - bf2f(hb));
        }
        size_t ob = (size_t)col * NN + mt * 32 + half * 16;
        *(uint4*)(Zthi + ob)     = *(const uint4*)&hu[0];
        *(uint4*)(Zthi + ob + 8) = *(const uint4*)&hu[8];
        *(uint4*)(Ztlo + ob)     = *(const uint4*)&lu[0];
        *(uint4*)(Ztlo + ob + 8) = *(const uint4*)&lu[8];
    }
}

// ---- D4: gemm_dual L0 (blocks 0..255) + CSR fill (blocks 256..767) ------
__global__ void __launch_bounds__(256) k_gemm_fill(
        const float* __restrict__ Ap, const float* __restrict__ Aa,
        const float* __restrict__ W, float* __restrict__ Zp,
        unsigned short* __restrict__ Zthi, unsigned short* __restrict__ Ztlo,
        int K, int relu, int aparts, int apstride,
        const int* __restrict__ ei, int* __restrict__ rowfill,
        int* __restrict__ csrcol) {
    __shared__ float Alp[32][68];
    __shared__ float Ala[32][68];
    __shared__ float Wl[64][132];
    int blk = blockIdx.x, t = threadIdx.x;
    if (blk < 256) {
        gemm_dual_body(blk, t, Ap, Aa, W, Zp, Zthi, Ztlo, K, relu, aparts, apstride,
                       Alp, Ala, Wl);
    } else {
        int e = (blk - 256) * 256 + t;
        int r = ei[e], c = ei[EE + e];
        int pos = atomicAdd(&rowfill[r], 1);
        csrcol[pos] = c;
    }
}

// plain gemm_dual for D6/D8
__global__ void __launch_bounds__(256) k_gemm_dual(
        const float* __restrict__ Ap, const float* __restrict__ Aa,
        const float* __restrict__ W, float* __restrict__ Zp,
        unsigned short* __restrict__ Zthi, unsigned short* __restrict__ Ztlo,
        int K, int relu, int aparts, int apstride) {
    __shared__ float Alp[32][68];
    __shared__ float Ala[32][68];
    __shared__ float Wl[64][132];
    gemm_dual_body(blockIdx.x, threadIdx.x, Ap, Aa, W, Zp, Zthi, Ztlo,
                   K, relu, aparts, apstride, Alp, Ala, Wl);
}

// ---- mfma + spmm (+ optional adj_write) fused dispatch ------------------
// blocks [0,512): mfma; [512,4608): spmm; [4608,4608+adjrows): adj_write
__global__ void __launch_bounds__(256) k_layer(
        const unsigned char* __restrict__ padjbits,
        const unsigned short* __restrict__ Zthi,
        const unsigned short* __restrict__ Ztlo,
        float* __restrict__ Sp,
        const int* __restrict__ rowptr, const int* __restrict__ csrcol,
        const float* __restrict__ Z, float* __restrict__ S,
        float* __restrict__ adj, int adjrows) {
    __shared__ __align__(16) char sm[128 * 72 * 2 * 2];  // 36864 B
    int blk = blockIdx.x, t = threadIdx.x;
    if (blk < 512) {
        unsigned short* Bh = (unsigned short*)sm;
        unsigned short* Bl = (unsigned short*)(sm + 128 * 72 * 2);
        int mt = blk >> 3, sk = blk & 7;
        int w = t >> 6, lane = t & 63;
        int quad = lane >> 4, l15 = lane & 15;
        f32x4 acc[2][8];
        #pragma unroll
        for (int m = 0; m < 2; ++m)
            #pragma unroll
            for (int i = 0; i < 8; ++i) acc[m][i] = (f32x4){0.f, 0.f, 0.f, 0.f};
        int bn = t >> 1, bq = t & 1;
        const unsigned short* zh = Zthi + (size_t)bn * NN + bq * 32;
        const unsigned short* zl = Ztlo + (size_t)bn * NN + bq * 32;
        int row0 = mt * 128 + w * 32 + l15;
        const ull* ab0 = (const ull*)(padjbits + (size_t)row0 * (NN / 8) + sk * 128);
        const ull* ab1 = (const ull*)(padjbits + (size_t)(row0 + 16) * (NN / 8) + sk * 128);
        int ldsw = bn * 72 + bq * 32;
        int bmb = l15 * 72 + quad * 8;
        for (int st = 0; st < 16; ++st) {
            int k = sk * 1024 + st * 64;
            ull bits0 = ab0[st];
            ull bits1 = ab1[st];
            *(uint4*)(Bh + ldsw + 0)  = *(const uint4*)(zh + k);
            *(uint4*)(Bh + ldsw + 8)  = *(const uint4*)(zh + k + 8);
            *(uint4*)(Bh + ldsw + 16) = *(const uint4*)(zh + k + 16);
            *(uint4*)(Bh + ldsw + 24) = *(const uint4*)(zh + k + 24);
            *(uint4*)(Bl + ldsw + 0)  = *(const uint4*)(zl + k);
            *(uint4*)(Bl + ldsw + 8)  = *(const uint4*)(zl + k + 8);
            *(uint4*)(Bl + ldsw + 16) = *(const uint4*)(zl + k + 16);
            *(uint4*)(Bl + ldsw + 24) = *(const uint4*)(zl + k + 24);
            __syncthreads();
            #pragma unroll
            for (int ksub = 0; ksub < 2; ++ksub) {
                unsigned b0 = ((unsigned)(bits0 >> (ksub * 32)) >> (quad * 8)) & 0xFFu;
                unsigned b1 = ((unsigned)(bits1 >> (ksub * 32)) >> (quad * 8)) & 0xFFu;
                short8 a0, a1;
                #pragma unroll
                for (int j = 0; j < 8; ++j) {
                    a0[j] = (b0 & (1u << j)) ? (short)0x3F80 : (short)0;
                    a1[j] = (b1 & (1u << j)) ? (short)0x3F80 : (short)0;
                }
                #pragma unroll
                for (int nt = 0; nt < 8; ++nt) {
                    short8 fh = *(const short8*)(Bh + nt * 16 * 72 + bmb + ksub * 32);
                    short8 fl = *(const short8*)(Bl + nt * 16 * 72 + bmb + ksub * 32);
                    acc[0][nt] = __builtin_amdgcn_mfma_f32_16x16x32_bf16(a0, fh, acc[0][nt], 0, 0, 0);
                    acc[0][nt] = __builtin_amdgcn_mfma_f32_16x16x32_bf16(a0, fl, acc[0][nt], 0, 0, 0);
                    acc[1][nt] = __builtin_amdgcn_mfma_f32_16x16x32_bf16(a1, fh, acc[1][nt], 0, 0, 0);
                    acc[1][nt] = __builtin_amdgcn_mfma_f32_16x16x32_bf16(a1, fl, acc[1][nt], 0, 0, 0);
                }
            }
            __syncthreads();
        }
        int dc = l15, dr = quad * 4;
        float* base = Sp + (size_t)sk * NN * HH + (size_t)(mt * 128 + w * 32 + dr) * HH;
        #pragma unroll
        for (int m = 0; m < 2; ++m)
            #pragma unroll
            for (int nt = 0; nt < 8; ++nt)
                #pragma unroll
                for (int r = 0; r < 4; ++r)
                    base[(size_t)(m * 16 + r) * HH + nt * 16 + dc] = acc[m][nt][r];
    } else if (blk < 4608) {
        int bid = blk - 512;
        int row = bid * 2 + (t >> 7);
        int col = t & 127;
        int start = rowptr[row], end = rowptr[row + 1];
        float s = 0.f;
        if (start < end) {
            int c = csrcol[start];
            for (int e = start; e < end; ++e) {
                int cn = (e + 1 < end) ? csrcol[e + 1] : 0;
                s += Z[(size_t)c * HH + col];
                c = cn;
            }
        }
        S[(size_t)row * HH + col] = s;
    } else {
        int* cnt = (int*)sm;  // 32 KB
        int row = blk - 4608;
        int4 z = make_int4(0, 0, 0, 0);
        #pragma unroll
        for (int i = 0; i < 8; ++i) *(int4*)&cnt[(i * 256 + t) * 4] = z;
        __syncthreads();
        int start = rowptr[row], end = rowptr[row + 1];
        for (int e = start + t; e < end; e += 256) atomicAdd(&cnt[csrcol[e]], 1);
        __syncthreads();
        float* dst = adj + (size_t)row * NN;
        #pragma unroll
        for (int i = 0; i < 8; ++i) {
            int p = i * 1024 + t * 4;
            float4 f;
            f.x = (float)cnt[p + 0]; f.y = (float)cnt[p + 1];
            f.z = (float)cnt[p + 2]; f.w = (float)cnt[p + 3];
            *(float4*)(dst + p) = f;
        }
    }
}

// ---- D10: fused pools ---------------------------------------------------
__global__ void __launch_bounds__(256) k_pool2(const float* __restrict__ S,
                                               const float* __restrict__ Sp,
                                               const float* __restrict__ mlpW,
                                               const float* __restrict__ mlpb,
                                               float* __restrict__ pred,
                                               float* __restrict__ augp,
                                               int apstride) {
    __shared__ float ps[256], pm[256], pl[256], r0[256], r1[256];
    int aug = blockIdx.x >> 5, g = blockIdx.x & 31, t = threadIdx.x;
    const float* Sb = aug ? Sp : S;
    int parts = aug ? 8 : 1;
    float* outp = aug ? augp : pred;
    int col = t & 127, half = t >> 7;
    const float* base = Sb + (size_t)(g * CC + half * 128) * HH + col;
    float sum = 0.f, mx = -3.0e38f;
    for (int rr = 0; rr < 128; ++rr) {
        float v = base[(size_t)rr * HH];
        for (int p = 1; p < parts; ++p) v += base[(size_t)p * apstride + (size_t)rr * HH];
        v = fmaxf(v, 0.f);
        sum += v;
        mx = fmaxf(mx, v);
    }
    ps[t] = sum; pm[t] = mx;
    __syncthreads();
    if (half == 0) {
        pl[col] = (ps[col] + ps[col + 128]) * (1.0f / 256.0f);
        pl[col + 128] = fmaxf(pm[col], pm[col + 128]);
    }
    __syncthreads();
    r0[t] = pl[t] * mlpW[t * 2 + 0];
    r1[t] = pl[t] * mlpW[t * 2 + 1];
    __syncthreads();
    for (int sft = 128; sft > 0; sft >>= 1) {
        if (t < sft) { r0[t] += r0[t + sft]; r1[t] += r1[t + sft]; }
        __syncthreads();
    }
    if (t == 0) {
        float l0 = r0[0] + mlpb[0];
        float l1 = r1[0] + mlpb[1];
        outp[g * 2 + 0] = 1.0f / (1.0f + expf(-l0));
        outp[g * 2 + 1] = 1.0f / (1.0f + expf(-l1));
    }
}

extern "C" void kernel_launch(void* const* d_in, const int* in_sizes, int n_in,
                              void* d_out, int out_size, void* d_ws, size_t ws_size,
                              hipStream_t stream) {
    (void)in_sizes; (void)n_in; (void)out_size; (void)ws_size;
    const float* x     = (const float*)d_in[0];
    const int*   ei    = (const int*)d_in[1];
    const int*   gid   = (const int*)d_in[2];
    const float* pertW = (const float*)d_in[4];
    const float* pertB = (const float*)d_in[5];
    const float* maskW = (const float*)d_in[6];
    const float* w0    = (const float*)d_in[7];
    const float* w1    = (const float*)d_in[8];
    const float* w2    = (const float*)d_in[9];
    const float* mlpW  = (const float*)d_in[10];
    const float* mlpb  = (const float*)d_in[11];

    float* out  = (float*)d_out;
    float* adj  = out;
    float* padj = out + (size_t)NN * NN;
    float* Mo   = out + 2 * (size_t)NN * NN;
    float* pred = Mo + (size_t)NN * CC;
    float* augp = pred + (size_t)BBg * 2;
    float* xm   = augp + (size_t)BBg * 2;

    char* ws = (char*)d_ws;
    int*            colcnt   = (int*)ws;                            // 1MB
    int*            rowcnt   = (int*)(ws + (1 << 20));              // 32KB (contig w/ colcnt)
    int*            rowptr   = (int*)(ws + (1 << 20) + (64 << 10)); // 33KB
    int*            rowfill  = (int*)(ws + (1 << 20) + (128 << 10));// 32KB
    unsigned char*  coljs    = (unsigned char*)(ws + (2 << 20));    // 4MB
    int*            csrcol   = (int*)(ws + (6 << 20));              // 512KB
    float*          Z        = (float*)(ws + (7 << 20));            // 4MB
    float*          S        = (float*)(ws + (11 << 20));           // 4MB
    unsigned short* Zthi     = (unsigned short*)(ws + (15 << 20));  // 2MB
    unsigned short* Ztlo     = (unsigned short*)(ws + (17 << 20));  // 2MB
    float*          Sp       = (float*)(ws + (19 << 20));           // 32MB (8 partials)
    unsigned char*  padjbits = (unsigned char*)(ws + (51 << 20));   // 8MB
    const int PS = NN * HH;  // partial stride (elements)

    // D1: zero colcnt + rowcnt
    hipMemsetAsync(colcnt, 0, (1 << 20) + (32 << 10), stream);
    // D2: hist + mask
    k_hist_mask<<<512 + 2048, 256, 0, stream>>>(ei, rowcnt, colcnt, coljs,
                                                maskW, gid, x, Mo, xm);
    // D3: scan + pertadj
    k_scan_pertadj<<<1025, 256, 0, stream>>>(rowcnt, rowptr, rowfill,
                                             pertW, pertB, gid, colcnt, coljs,
                                             padj, padjbits);
    // D4: gemm_dual L0 + CSR fill
    k_gemm_fill<<<768, 256, 0, stream>>>(x, xm, w0, Z, Zthi, Ztlo, 256, 0, 1, 0,
                                         ei, rowfill, csrcol);
    // D5: mfma L0 + spmm L0 + adj_write
    k_layer<<<512 + 4096 + 8192, 256, 0, stream>>>(padjbits, Zthi, Ztlo, Sp,
                                                   rowptr, csrcol, Z, S, adj, NN);
    // D6: gemm_dual L1
    k_gemm_dual<<<256, 256, 0, stream>>>(S, Sp, w1, Z, Zthi, Ztlo, 128, 1, 8, PS);
    // D7: mfma L1 + spmm L1
    k_layer<<<512 + 4096, 256, 0, stream>>>(padjbits, Zthi, Ztlo, Sp,
                                            rowptr, csrcol, Z, S, adj, 0);
    // D8: gemm_dual L2
    k_gemm_dual<<<256, 256, 0, stream>>>(S, Sp, w2, Z, Zthi, Ztlo, 128, 1, 8, PS);
    // D9: mfma L2 + spmm L2
    k_layer<<<512 + 4096, 256, 0, stream>>>(padjbits, Zthi, Ztlo, Sp,
                                            rowptr, csrcol, Z, S, adj, 0);
    // D10: pools
    k_pool2<<<64, 256, 0, stream>>>(S, Sp, mlpW, mlpb, pred, augp, PS);
}

// Round 5
// 1064.233 us; speedup vs baseline: 1.1074x; 1.1074x over previous
//
#include <hip/hip_runtime.h>
#include <hip/hip_bf16.h>

#define NN 8192     // total nodes
#define CC 256      // nodes per graph == in_channels
#define BBg 32      // graphs
#define HH 128      // hidden
#define EE 131072   // edges

typedef __attribute__((ext_vector_type(8))) short short8;
typedef __attribute__((ext_vector_type(4))) float f32x4;
typedef unsigned long long ull;

// Replicate fp32 hard_where(sigmoid(v)) boundary exactly (see round-0 notes).
__device__ __forceinline__ float hard01(float v) {
    if (v >= 1e-6f) return 1.0f;
    if (v <= 0.0f) return 0.0f;
    float ef = (float)exp(-(double)v);
    float s = 1.0f / (1.0f + ef);
    return (s > 0.5f) ? 1.0f : 0.0f;
}

__device__ __forceinline__ unsigned short f2bf(float f) {
    unsigned u = __float_as_uint(f);
    u += 0x7FFFu + ((u >> 16) & 1u);   // RNE
    return (unsigned short)(u >> 16);
}
__device__ __forceinline__ float bf2f(unsigned short b) {
    return __uint_as_float(((unsigned)b) << 16);
}

// ---- CSR build ----------------------------------------------------------
__global__ void k_hist(const int* __restrict__ ei, int* __restrict__ rowcnt,
                       int* __restrict__ colcnt, unsigned char* __restrict__ coljs) {
    int e = blockIdx.x * 256 + threadIdx.x;
    if (e >= EE) return;
    int r = ei[e], c = ei[EE + e];
    atomicAdd(&rowcnt[r], 1);
    int idx = (r >> 8) * NN + c;
    int slot = atomicAdd(&colcnt[idx], 1);
    if (slot < 16) coljs[(size_t)idx * 16 + slot] = (unsigned char)(r & 255);
}

__global__ void k_scan(const int* __restrict__ rowcnt, int* __restrict__ rowptr,
                       int* __restrict__ rowfill) {
    __shared__ int sums[256];
    int t = threadIdx.x;
    int base = t * 32;
    int loc[32];
    int s = 0;
    #pragma unroll
    for (int i = 0; i < 32; ++i) { loc[i] = s; s += rowcnt[base + i]; }
    sums[t] = s;
    __syncthreads();
    if (t == 0) {
        int a = 0;
        for (int i = 0; i < 256; ++i) { int v = sums[i]; sums[i] = a; a += v; }
        rowptr[NN] = a;
    }
    __syncthreads();
    int off = sums[t];
    #pragma unroll
    for (int i = 0; i < 32; ++i) {
        rowptr[base + i] = off + loc[i];
        rowfill[base + i] = off + loc[i];
    }
}

__global__ void k_fill(const int* __restrict__ ei, int* __restrict__ rowfill,
                       int* __restrict__ csrcol) {
    int e = blockIdx.x * 256 + threadIdx.x;
    if (e >= EE) return;
    int r = ei[e], c = ei[EE + e];
    int pos = atomicAdd(&rowfill[r], 1);
    csrcol[pos] = c;
}

// K2: stream-write adj from CSR (LDS row accumulator)
__global__ void __launch_bounds__(256) k_adj_write(const int* __restrict__ rowptr,
                                                   const int* __restrict__ csrcol,
                                                   float* __restrict__ adj) {
    __shared__ int cnt[NN];
    int row = blockIdx.x, t = threadIdx.x;
    int4 z = make_int4(0, 0, 0, 0);
    #pragma unroll
    for (int i = 0; i < 8; ++i) *(int4*)&cnt[(i * 256 + t) * 4] = z;
    __syncthreads();
    int start = rowptr[row], end = rowptr[row + 1];
    for (int e = start + t; e < end; e += 256) atomicAdd(&cnt[csrcol[e]], 1);
    __syncthreads();
    float* dst = adj + (size_t)row * NN;
    #pragma unroll
    for (int i = 0; i < 8; ++i) {
        int p = i * 1024 + t * 4;
        float4 f;
        f.x = (float)cnt[p + 0]; f.y = (float)cnt[p + 1];
        f.z = (float)cnt[p + 2]; f.w = (float)cnt[p + 3];
        *(float4*)(dst + p) = f;
    }
}

// K3: M = hard01(mask_W[graph_id] rows), x_masked = M*x
__global__ void k_mask(const float* __restrict__ maskW, const int* __restrict__ gid,
                       const float* __restrict__ x, float* __restrict__ Mo,
                       float* __restrict__ xm) {
    int i = blockIdx.x * 256 + threadIdx.x;
    int base = i * 4;
    int r = base >> 8;
    int c = base & 255;
    int g = gid[r >> 8];
    float4 mv = *(const float4*)(maskW + ((size_t)g << 16) + ((size_t)(r & 255) << 8) + c);
    float4 xv = *(const float4*)(x + ((size_t)r << 8) + c);
    float4 m, o;
    m.x = hard01(mv.x); m.y = hard01(mv.y); m.z = hard01(mv.z); m.w = hard01(mv.w);
    o.x = m.x * xv.x; o.y = m.y * xv.y; o.z = m.z * xv.z; o.w = m.w * xv.w;
    *(float4*)(Mo + ((size_t)r << 8) + c) = m;
    *(float4*)(xm + ((size_t)r << 8) + c) = o;
}

// K4: pert_adj -> fp32 padj (d_out) + 1-bit packed padjbits (ws).
// grid 1024 = b(32) x rt(8) x nc(4); thread covers 8 rows x 8 contiguous cols/it,
// stores merged as 2 adjacent float4 per row.
__global__ void __launch_bounds__(256) k_pertadj(const float* __restrict__ pertW,
                                                 const float* __restrict__ pertB,
                                                 const int* __restrict__ gid,
                                                 const int* __restrict__ colcnt,
                                                 const unsigned char* __restrict__ coljs,
                                                 float* __restrict__ padj,
                                                 unsigned char* __restrict__ padjbits) {
    __shared__ float Pl[32][257];
    int nc = blockIdx.x & 3, rt = (blockIdx.x >> 2) & 7, b = blockIdx.x >> 5;
    int t = threadIdx.x;
    int g = gid[b];
    const float* src = pertW + ((size_t)g << 16) + (size_t)rt * 32 * CC;
    #pragma unroll 4
    for (int i = 0; i < 32; ++i) Pl[i][t] = src[i * CC + t];
    __syncthreads();
    int ty = t >> 6, tx = t & 63;          // ty: 8-row group; tx: 8-col group
    int ro = ty * 8;
    const float* bsrc = pertB + ((size_t)g << 16) + (size_t)(rt * 32 + ro) * CC;
    for (int it = 0; it < 4; ++it) {
        int n0 = nc * 2048 + it * 512 + tx * 8;
        float s[8][8];
        #pragma unroll
        for (int ii = 0; ii < 8; ++ii)
            #pragma unroll
            for (int cc = 0; cc < 8; ++cc) s[ii][cc] = 0.0f;
        #pragma unroll
        for (int half = 0; half < 2; ++half) {
            int n = n0 + half * 4;
            int cidx = b * NN + n;
            int4 cnt4 = *(const int4*)(colcnt + cidx);
            const uint4* jp = (const uint4*)(coljs + (size_t)cidx * 16);
            #pragma unroll
            for (int cc = 0; cc < 4; ++cc) {
                int cnt = (&cnt4.x)[cc];
                cnt = cnt > 16 ? 16 : cnt;
                if (cnt == 0) continue;
                uint4 jv = jp[cc];
                for (int q = 0; q < cnt; ++q) {
                    unsigned word = (q < 8) ? ((q < 4) ? jv.x : jv.y)
                                            : ((q < 12) ? jv.z : jv.w);
                    int j = (word >> ((q & 3) * 8)) & 255;
                    #pragma unroll
                    for (int ii = 0; ii < 8; ++ii) s[ii][half * 4 + cc] += Pl[ro + ii][j];
                }
            }
        }
        bool diag = ((n0 >> 8) == b);
        #pragma unroll
        for (int ii = 0; ii < 8; ++ii) {
            if (diag) {
                const float* bp = bsrc + (size_t)ii * CC + (n0 & 255);
                #pragma unroll
                for (int cc = 0; cc < 8; ++cc) s[ii][cc] += bp[cc];
            }
            float f[8];
            unsigned byte = 0;
            #pragma unroll
            for (int cc = 0; cc < 8; ++cc) {
                f[cc] = hard01(s[ii][cc]);
                if (f[cc] != 0.f) byte |= (1u << cc);
            }
            size_t ob = (size_t)(b * CC + rt * 32 + ro + ii) * NN + n0;
            float4 f0, f1;
            f0.x = f[0]; f0.y = f[1]; f0.z = f[2]; f0.w = f[3];
            f1.x = f[4]; f1.y = f[5]; f1.z = f[6]; f1.w = f[7];
            *(float4*)(padj + ob) = f0;
            *(float4*)(padj + ob + 4) = f1;
            size_t bb = (size_t)(b * CC + rt * 32 + ro + ii) * (NN / 8)
                        + nc * 256 + it * 64 + tx;
            padjbits[bb] = (unsigned char)byte;
        }
    }
}

// K5: dual GEMM: Zp = relu?(Ap)@W  and  Zt(hi/lo bf16, transposed) = relu?(sum Aa)@W
__global__ void __launch_bounds__(256) k_gemm_dual(const float* __restrict__ Ap,
                                                   const float* __restrict__ Aa,
                                                   const float* __restrict__ W,
                                                   float* __restrict__ Zp,
                                                   unsigned short* __restrict__ Zthi,
                                                   unsigned short* __restrict__ Ztlo,
                                                   int K, int relu, int aparts, int apstride) {
    __shared__ float Alp[32][68];
    __shared__ float Ala[32][68];
    __shared__ float Wl[64][132];
    int mt = blockIdx.x;
    int t = threadIdx.x;
    int ty = t >> 3, tx = t & 7;
    float accp[16], acca[16];
    #pragma unroll
    for (int u = 0; u < 16; ++u) { accp[u] = 0.0f; acca[u] = 0.0f; }
    for (int kc = 0; kc < K; kc += 64) {
        int row = t >> 3, q = t & 7;
        {
            const float* ap = Ap + (size_t)(mt * 32 + row) * K + kc + q * 8;
            float4 f0 = *(const float4*)ap;
            float4 f1 = *(const float4*)(ap + 4);
            if (relu) {
                f0.x = fmaxf(f0.x, 0.f); f0.y = fmaxf(f0.y, 0.f);
                f0.z = fmaxf(f0.z, 0.f); f0.w = fmaxf(f0.w, 0.f);
                f1.x = fmaxf(f1.x, 0.f); f1.y = fmaxf(f1.y, 0.f);
                f1.z = fmaxf(f1.z, 0.f); f1.w = fmaxf(f1.w, 0.f);
            }
            *(float4*)&Alp[row][q * 8] = f0;
            *(float4*)&Alp[row][q * 8 + 4] = f1;
        }
        {
            const float* ap = Aa + (size_t)(mt * 32 + row) * K + kc + q * 8;
            float4 f0 = *(const float4*)ap;
            float4 f1 = *(const float4*)(ap + 4);
            for (int p = 1; p < aparts; ++p) {
                float4 g0 = *(const float4*)(ap + (size_t)p * apstride);
                float4 g1 = *(const float4*)(ap + (size_t)p * apstride + 4);
                f0.x += g0.x; f0.y += g0.y; f0.z += g0.z; f0.w += g0.w;
                f1.x += g1.x; f1.y += g1.y; f1.z += g1.z; f1.w += g1.w;
            }
            if (relu) {
                f0.x = fmaxf(f0.x, 0.f); f0.y = fmaxf(f0.y, 0.f);
                f0.z = fmaxf(f0.z, 0.f); f0.w = fmaxf(f0.w, 0.f);
                f1.x = fmaxf(f1.x, 0.f); f1.y = fmaxf(f1.y, 0.f);
                f1.z = fmaxf(f1.z, 0.f); f1.w = fmaxf(f1.w, 0.f);
            }
            *(float4*)&Ala[row][q * 8] = f0;
            *(float4*)&Ala[row][q * 8 + 4] = f1;
        }
        {
            int wrow = t >> 2, wq = t & 3;
            const float* wp = W + (size_t)(kc + wrow) * HH + wq * 32;
            #pragma unroll
            for (int u = 0; u < 32; u += 4)
                *(float4*)&Wl[wrow][wq * 32 + u] = *(const float4*)(wp + u);
        }
        __syncthreads();
        #pragma unroll 2
        for (int kk = 0; kk < 64; ++kk) {
            float a = Alp[ty][kk];
            float b2 = Ala[ty][kk];
            #pragma unroll
            for (int u = 0; u < 16; u += 4) {
                float4 wv = *(const float4*)(&Wl[kk][tx * 16 + u]);
                accp[u + 0] += a * wv.x; accp[u + 1] += a * wv.y;
                accp[u + 2] += a * wv.z; accp[u + 3] += a * wv.w;
                acca[u + 0] += b2 * wv.x; acca[u + 1] += b2 * wv.y;
                acca[u + 2] += b2 * wv.z; acca[u + 3] += b2 * wv.w;
            }
        }
        __syncthreads();
    }
    {
        float* cp = Zp + (size_t)(mt * 32 + ty) * HH + tx * 16;
        #pragma unroll
        for (int u = 0; u < 16; u += 4) {
            float4 f;
            f.x = accp[u]; f.y = accp[u + 1]; f.z = accp[u + 2]; f.w = accp[u + 3];
            *(float4*)(cp + u) = f;
        }
    }
    {
        __syncthreads();
        float* Tl = &Wl[0][0];  // reuse as [32][132]
        #pragma unroll
        for (int u = 0; u < 16; ++u) Tl[ty * 132 + tx * 16 + u] = acca[u];
        __syncthreads();
        int col = t >> 1, half = t & 1;
        unsigned short hu[16] __attribute__((aligned(16)));
        unsigned short lu[16] __attribute__((aligned(16)));
        #pragma unroll
        for (int rr = 0; rr < 16; ++rr) {
            float v = Tl[(half * 16 + rr) * 132 + col];
            unsigned short hb = f2bf(v);
            hu[rr] = hb;
            lu[rr] = f2bf(v - bf2f(hb));
        }
        size_t ob = (size_t)col * NN + mt * 32 + half * 16;
        *(uint4*)(Zthi + ob)     = *(const uint4*)&hu[0];
        *(uint4*)(Zthi + ob + 8) = *(const uint4*)&hu[8];
        *(uint4*)(Ztlo + ob)     = *(const uint4*)&lu[0];
        *(uint4*)(Ztlo + ob + 8) = *(const uint4*)&lu[8];
    }
}

// K6: S = adj @ Z by CSR gather (no atomics), 2-way ILP
__global__ void k_spmm_gather(const int* __restrict__ rowptr,
                              const int* __restrict__ csrcol,
                              const float* __restrict__ Z,
                              float* __restrict__ S) {
    int t = threadIdx.x;
    int row = blockIdx.x * 2 + (t >> 7);
    int col = t & 127;
    int start = rowptr[row], end = rowptr[row + 1];
    float s0 = 0.f, s1 = 0.f;
    int e = start;
    for (; e + 2 <= end; e += 2) {
        int c0 = csrcol[e], c1 = csrcol[e + 1];
        s0 += Z[(size_t)c0 * HH + col];
        s1 += Z[(size_t)c1 * HH + col];
    }
    if (e < end) s0 += Z[(size_t)csrcol[e] * HH + col];
    S[(size_t)row * HH + col] = s0 + s1;
}

// K7: Sp[sk] = pert_adj(bits, k-slice sk) @ Z.
// 4 m-tiles/wave (256-row blocks), double-buffered 32-k LDS B tile.
// grid 256 = mt(32) x sk(8).
__global__ void __launch_bounds__(256) k_mfma_spmm(const unsigned char* __restrict__ padjbits,
                                                   const unsigned short* __restrict__ Zthi,
                                                   const unsigned short* __restrict__ Ztlo,
                                                   float* __restrict__ Sp) {
    __shared__ unsigned short Bh[2][128 * 40];
    __shared__ unsigned short Bl[2][128 * 40];
    int mt = blockIdx.x >> 3, sk = blockIdx.x & 7;
    int t = threadIdx.x, w = t >> 6, lane = t & 63;
    int quad = lane >> 4, l15 = lane & 15;
    f32x4 acc[4][8];
    #pragma unroll
    for (int m = 0; m < 4; ++m)
        #pragma unroll
        for (int i = 0; i < 8; ++i) acc[m][i] = (f32x4){0.f, 0.f, 0.f, 0.f};
    int bn = t >> 1, bq = t & 1;
    const unsigned short* zh = Zthi + (size_t)bn * NN + sk * 1024 + bq * 16;
    const unsigned short* zl = Ztlo + (size_t)bn * NN + sk * 1024 + bq * 16;
    int row0 = mt * 256 + w * 64 + l15;
    const unsigned* ab[4];
    #pragma unroll
    for (int m = 0; m < 4; ++m)
        ab[m] = (const unsigned*)(padjbits + (size_t)(row0 + m * 16) * (NN / 8)) + sk * 32;
    int ldsw = bn * 40 + bq * 16;
    int bmb = l15 * 40 + quad * 8;
    uint4 rh0, rh1, rl0, rl1;
    unsigned bits[4], nbits[4];
    // prologue: stage step 0
    rh0 = *(const uint4*)(zh + 0);
    rh1 = *(const uint4*)(zh + 8);
    rl0 = *(const uint4*)(zl + 0);
    rl1 = *(const uint4*)(zl + 8);
    #pragma unroll
    for (int m = 0; m < 4; ++m) bits[m] = ab[m][0];
    *(uint4*)(&Bh[0][ldsw + 0]) = rh0;
    *(uint4*)(&Bh[0][ldsw + 8]) = rh1;
    *(uint4*)(&Bl[0][ldsw + 0]) = rl0;
    *(uint4*)(&Bl[0][ldsw + 8]) = rl1;
    __syncthreads();
    for (int st = 0; st < 32; ++st) {
        int cur = st & 1;
        if (st < 31) {
            int k = (st + 1) * 32;
            rh0 = *(const uint4*)(zh + k);
            rh1 = *(const uint4*)(zh + k + 8);
            rl0 = *(const uint4*)(zl + k);
            rl1 = *(const uint4*)(zl + k + 8);
            #pragma unroll
            for (int m = 0; m < 4; ++m) nbits[m] = ab[m][st + 1];
        }
        short8 a[4];
        #pragma unroll
        for (int m = 0; m < 4; ++m) {
            unsigned byte = (bits[m] >> (quad * 8)) & 0xFFu;
            #pragma unroll
            for (int j = 0; j < 8; ++j)
                a[m][j] = (byte & (1u << j)) ? (short)0x3F80 : (short)0;
        }
        #pragma unroll
        for (int nt = 0; nt < 8; ++nt) {
            short8 fh = *(const short8*)(&Bh[cur][nt * 16 * 40 + bmb]);
            short8 fl = *(const short8*)(&Bl[cur][nt * 16 * 40 + bmb]);
            #pragma unroll
            for (int m = 0; m < 4; ++m) {
                acc[m][nt] = __builtin_amdgcn_mfma_f32_16x16x32_bf16(a[m], fh, acc[m][nt], 0, 0, 0);
                acc[m][nt] = __builtin_amdgcn_mfma_f32_16x16x32_bf16(a[m], fl, acc[m][nt], 0, 0, 0);
            }
        }
        if (st < 31) {
            *(uint4*)(&Bh[1 - cur][ldsw + 0]) = rh0;
            *(uint4*)(&Bh[1 - cur][ldsw + 8]) = rh1;
            *(uint4*)(&Bl[1 - cur][ldsw + 0]) = rl0;
            *(uint4*)(&Bl[1 - cur][ldsw + 8]) = rl1;
            #pragma unroll
            for (int m = 0; m < 4; ++m) bits[m] = nbits[m];
        }
        __syncthreads();
    }
    int dc = l15, dr = quad * 4;
    float* base = Sp + (size_t)sk * NN * HH + (size_t)(mt * 256 + w * 64 + dr) * HH;
    #pragma unroll
    for (int m = 0; m < 4; ++m)
        #pragma unroll
        for (int nt = 0; nt < 8; ++nt)
            #pragma unroll
            for (int r = 0; r < 4; ++r)
                base[(size_t)(m * 16 + r) * HH + nt * 16 + dc] = acc[m][nt][r];
}

// K8: fused pools: block 0..31 pred (parts=1), 32..63 aug (parts=8)
__global__ void __launch_bounds__(256) k_pool2(const float* __restrict__ S,
                                               const float* __restrict__ Sp,
                                               const float* __restrict__ mlpW,
                                               const float* __restrict__ mlpb,
                                               float* __restrict__ pred,
                                               float* __restrict__ augp,
                                               int apstride) {
    __shared__ float ps[256], pm[256], pl[256], r0[256], r1[256];
    int aug = blockIdx.x >> 5, g = blockIdx.x & 31, t = threadIdx.x;
    const float* Sb = aug ? Sp : S;
    int parts = aug ? 8 : 1;
    float* outp = aug ? augp : pred;
    int col = t & 127, half = t >> 7;
    const float* base = Sb + (size_t)(g * CC + half * 128) * HH + col;
    float sum = 0.f, mx = -3.0e38f;
    for (int rr = 0; rr < 128; ++rr) {
        float v = base[(size_t)rr * HH];
        for (int p = 1; p < parts; ++p) v += base[(size_t)p * apstride + (size_t)rr * HH];
        v = fmaxf(v, 0.f);
        sum += v;
        mx = fmaxf(mx, v);
    }
    ps[t] = sum; pm[t] = mx;
    __syncthreads();
    if (half == 0) {
        pl[col] = (ps[col] + ps[col + 128]) * (1.0f / 256.0f);
        pl[col + 128] = fmaxf(pm[col], pm[col + 128]);
    }
    __syncthreads();
    r0[t] = pl[t] * mlpW[t * 2 + 0];
    r1[t] = pl[t] * mlpW[t * 2 + 1];
    __syncthreads();
    for (int sft = 128; sft > 0; sft >>= 1) {
        if (t < sft) { r0[t] += r0[t + sft]; r1[t] += r1[t + sft]; }
        __syncthreads();
    }
    if (t == 0) {
        float l0 = r0[0] + mlpb[0];
        float l1 = r1[0] + mlpb[1];
        outp[g * 2 + 0] = 1.0f / (1.0f + expf(-l0));
        outp[g * 2 + 1] = 1.0f / (1.0f + expf(-l1));
    }
}

extern "C" void kernel_launch(void* const* d_in, const int* in_sizes, int n_in,
                              void* d_out, int out_size, void* d_ws, size_t ws_size,
                              hipStream_t stream) {
    (void)in_sizes; (void)n_in; (void)out_size; (void)ws_size;
    const float* x     = (const float*)d_in[0];
    const int*   ei    = (const int*)d_in[1];
    const int*   gid   = (const int*)d_in[2];
    const float* pertW = (const float*)d_in[4];
    const float* pertB = (const float*)d_in[5];
    const float* maskW = (const float*)d_in[6];
    const float* w0    = (const float*)d_in[7];
    const float* w1    = (const float*)d_in[8];
    const float* w2    = (const float*)d_in[9];
    const float* mlpW  = (const float*)d_in[10];
    const float* mlpb  = (const float*)d_in[11];

    float* out  = (float*)d_out;
    float* adj  = out;
    float* padj = out + (size_t)NN * NN;
    float* Mo   = out + 2 * (size_t)NN * NN;
    float* pred = Mo + (size_t)NN * CC;
    float* augp = pred + (size_t)BBg * 2;
    float* xm   = augp + (size_t)BBg * 2;

    char* ws = (char*)d_ws;
    int*            colcnt   = (int*)ws;                            // 1MB
    int*            rowcnt   = (int*)(ws + (1 << 20));              // 32KB (contig w/ colcnt)
    int*            rowptr   = (int*)(ws + (1 << 20) + (64 << 10)); // 33KB
    int*            rowfill  = (int*)(ws + (1 << 20) + (128 << 10));// 32KB
    unsigned char*  coljs    = (unsigned char*)(ws + (2 << 20));    // 4MB
    int*            csrcol   = (int*)(ws + (6 << 20));              // 512KB
    float*          Z        = (float*)(ws + (7 << 20));            // 4MB
    float*          S        = (float*)(ws + (11 << 20));           // 4MB
    unsigned short* Zthi     = (unsigned short*)(ws + (15 << 20));  // 2MB
    unsigned short* Ztlo     = (unsigned short*)(ws + (17 << 20));  // 2MB
    float*          Sp       = (float*)(ws + (19 << 20));           // 32MB (8 partials)
    unsigned char*  padjbits = (unsigned char*)(ws + (51 << 20));   // 8MB
    const int PS = NN * HH;  // partial stride (elements)

    hipMemsetAsync(colcnt, 0, (1 << 20) + (32 << 10), stream);  // colcnt + rowcnt
    k_hist<<<EE / 256, 256, 0, stream>>>(ei, rowcnt, colcnt, coljs);
    k_scan<<<1, 256, 0, stream>>>(rowcnt, rowptr, rowfill);
    k_fill<<<EE / 256, 256, 0, stream>>>(ei, rowfill, csrcol);
    k_adj_write<<<NN, 256, 0, stream>>>(rowptr, csrcol, adj);
    k_mask<<<(NN * CC / 4) / 256, 256, 0, stream>>>(maskW, gid, x, Mo, xm);
    k_pertadj<<<1024, 256, 0, stream>>>(pertW, pertB, gid, colcnt, coljs, padj, padjbits);

    // layer 0
    k_gemm_dual<<<256, 256, 0, stream>>>(x, xm, w0, Z, Zthi, Ztlo, 256, 0, 1, 0);
    k_spmm_gather<<<NN / 2, 256, 0, stream>>>(rowptr, csrcol, Z, S);
    k_mfma_spmm<<<256, 256, 0, stream>>>(padjbits, Zthi, Ztlo, Sp);
    // layer 1
    k_gemm_dual<<<256, 256, 0, stream>>>(S, Sp, w1, Z, Zthi, Ztlo, 128, 1, 8, PS);
    k_spmm_gather<<<NN / 2, 256, 0, stream>>>(rowptr, csrcol, Z, S);
    k_mfma_spmm<<<256, 256, 0, stream>>>(padjbits, Zthi, Ztlo, Sp);
    // layer 2
    k_gemm_dual<<<256, 256, 0, stream>>>(S, Sp, w2, Z, Zthi, Ztlo, 128, 1, 8, PS);
    k_spmm_gather<<<NN / 2, 256, 0, stream>>>(rowptr, csrcol, Z, S);
    k_mfma_spmm<<<256, 256, 0, stream>>>(padjbits, Zthi, Ztlo, Sp);
    // pools
    k_pool2<<<64, 256, 0, stream>>>(S, Sp, mlpW, mlpb, pred, augp, PS);
}

// Round 6
// 998.630 us; speedup vs baseline: 1.1802x; 1.0657x over previous
//
#include <hip/hip_runtime.h>
#include <hip/hip_bf16.h>

#define NN 8192     // total nodes
#define CC 256      // nodes per graph == in_channels
#define BBg 32      // graphs
#define HH 128      // hidden
#define EE 131072   // edges

typedef __attribute__((ext_vector_type(8))) short short8;
typedef __attribute__((ext_vector_type(4))) float f32x4;
typedef unsigned long long ull;

// Replicate fp32 hard_where(sigmoid(v)) boundary exactly (see round-0 notes).
__device__ __forceinline__ float hard01(float v) {
    if (v >= 1e-6f) return 1.0f;
    if (v <= 0.0f) return 0.0f;
    float ef = (float)exp(-(double)v);
    float s = 1.0f / (1.0f + ef);
    return (s > 0.5f) ? 1.0f : 0.0f;
}

__device__ __forceinline__ unsigned short f2bf(float f) {
    unsigned u = __float_as_uint(f);
    u += 0x7FFFu + ((u >> 16) & 1u);   // RNE
    return (unsigned short)(u >> 16);
}
__device__ __forceinline__ float bf2f(unsigned short b) {
    return __uint_as_float(((unsigned)b) << 16);
}

// ---- D2: hist (blocks 0..511) + mask (blocks 512..2559) -----------------
__global__ void k_hist_mask(const int* __restrict__ ei, int* __restrict__ rowcnt,
                            int* __restrict__ colcnt, unsigned char* __restrict__ coljs,
                            const float* __restrict__ maskW, const int* __restrict__ gid,
                            const float* __restrict__ x, float* __restrict__ Mo,
                            float* __restrict__ xm) {
    int blk = blockIdx.x, t = threadIdx.x;
    if (blk < 512) {
        int e = blk * 256 + t;
        int r = ei[e], c = ei[EE + e];
        atomicAdd(&rowcnt[r], 1);
        int idx = (r >> 8) * NN + c;
        int slot = atomicAdd(&colcnt[idx], 1);
        if (slot < 16) coljs[(size_t)idx * 16 + slot] = (unsigned char)(r & 255);
    } else {
        int i = (blk - 512) * 256 + t;
        int base = i * 4;
        int r = base >> 8;
        int c = base & 255;
        int g = gid[r >> 8];
        float4 mv = *(const float4*)(maskW + ((size_t)g << 16) + ((size_t)(r & 255) << 8) + c);
        float4 xv = *(const float4*)(x + ((size_t)r << 8) + c);
        float4 m, o;
        m.x = hard01(mv.x); m.y = hard01(mv.y); m.z = hard01(mv.z); m.w = hard01(mv.w);
        o.x = m.x * xv.x; o.y = m.y * xv.y; o.z = m.z * xv.z; o.w = m.w * xv.w;
        *(float4*)(Mo + ((size_t)r << 8) + c) = m;
        *(float4*)(xm + ((size_t)r << 8) + c) = o;
    }
}

// ---- D3: scan (block 0) + pertadj (blocks 1..1024) ----------------------
__global__ void __launch_bounds__(256) k_scan_pertadj(
        const int* __restrict__ rowcnt, int* __restrict__ rowptr,
        int* __restrict__ rowfill,
        const float* __restrict__ pertW, const float* __restrict__ pertB,
        const int* __restrict__ gid, const int* __restrict__ colcnt,
        const unsigned char* __restrict__ coljs,
        float* __restrict__ padj, unsigned char* __restrict__ padjbits) {
    __shared__ float Pl[32][257];
    __shared__ int sums[256];
    int t = threadIdx.x;
    if (blockIdx.x == 0) {
        int base = t * 32;
        int loc[32];
        int s = 0;
        #pragma unroll
        for (int i = 0; i < 32; ++i) { loc[i] = s; s += rowcnt[base + i]; }
        sums[t] = s;
        __syncthreads();
        if (t == 0) {
            int a = 0;
            for (int i = 0; i < 256; ++i) { int v = sums[i]; sums[i] = a; a += v; }
            rowptr[NN] = a;
        }
        __syncthreads();
        int off = sums[t];
        #pragma unroll
        for (int i = 0; i < 32; ++i) {
            rowptr[base + i] = off + loc[i];
            rowfill[base + i] = off + loc[i];
        }
        return;
    }
    int bid = blockIdx.x - 1;
    int nc = bid & 3, rt = (bid >> 2) & 7, b = bid >> 5;
    int g = gid[b];
    const float* src = pertW + ((size_t)g << 16) + (size_t)rt * 32 * CC;
    #pragma unroll 4
    for (int i = 0; i < 32; ++i) Pl[i][t] = src[i * CC + t];
    __syncthreads();
    int ty = t >> 6, tx = t & 63;          // ty: 8-row group; tx: 8-col group
    int ro = ty * 8;
    const float* bsrc = pertB + ((size_t)g << 16) + (size_t)(rt * 32 + ro) * CC;
    for (int it = 0; it < 4; ++it) {
        int n0 = nc * 2048 + it * 512 + tx * 8;
        float s[8][8];
        #pragma unroll
        for (int ii = 0; ii < 8; ++ii)
            #pragma unroll
            for (int cc = 0; cc < 8; ++cc) s[ii][cc] = 0.0f;
        #pragma unroll
        for (int half = 0; half < 2; ++half) {
            int n = n0 + half * 4;
            int cidx = b * NN + n;
            int4 cnt4 = *(const int4*)(colcnt + cidx);
            const uint4* jp = (const uint4*)(coljs + (size_t)cidx * 16);
            #pragma unroll
            for (int cc = 0; cc < 4; ++cc) {
                int cnt = (&cnt4.x)[cc];
                cnt = cnt > 16 ? 16 : cnt;
                if (cnt == 0) continue;
                uint4 jv = jp[cc];
                for (int q = 0; q < cnt; ++q) {
                    unsigned word = (q < 8) ? ((q < 4) ? jv.x : jv.y)
                                            : ((q < 12) ? jv.z : jv.w);
                    int j = (word >> ((q & 3) * 8)) & 255;
                    #pragma unroll
                    for (int ii = 0; ii < 8; ++ii) s[ii][half * 4 + cc] += Pl[ro + ii][j];
                }
            }
        }
        bool diag = ((n0 >> 8) == b);
        #pragma unroll
        for (int ii = 0; ii < 8; ++ii) {
            if (diag) {
                const float* bp = bsrc + (size_t)ii * CC + (n0 & 255);
                #pragma unroll
                for (int cc = 0; cc < 8; ++cc) s[ii][cc] += bp[cc];
            }
            float f[8];
            unsigned byte = 0;
            #pragma unroll
            for (int cc = 0; cc < 8; ++cc) {
                f[cc] = hard01(s[ii][cc]);
                if (f[cc] != 0.f) byte |= (1u << cc);
            }
            size_t ob = (size_t)(b * CC + rt * 32 + ro + ii) * NN + n0;
            float4 f0, f1;
            f0.x = f[0]; f0.y = f[1]; f0.z = f[2]; f0.w = f[3];
            f1.x = f[4]; f1.y = f[5]; f1.z = f[6]; f1.w = f[7];
            *(float4*)(padj + ob) = f0;
            *(float4*)(padj + ob + 4) = f1;
            size_t bb = (size_t)(b * CC + rt * 32 + ro + ii) * (NN / 8)
                        + nc * 256 + it * 64 + tx;
            padjbits[bb] = (unsigned char)byte;
        }
    }
}

// ---- gemm_dual body -----------------------------------------------------
__device__ __forceinline__ void gemm_dual_body(
        int mt, int t,
        const float* __restrict__ Ap, const float* __restrict__ Aa,
        const float* __restrict__ W, float* __restrict__ Zp,
        unsigned short* __restrict__ Zthi, unsigned short* __restrict__ Ztlo,
        int K, int relu, int aparts, int apstride,
        float (*Alp)[68], float (*Ala)[68], float (*Wl)[132]) {
    int ty = t >> 3, tx = t & 7;
    float accp[16], acca[16];
    #pragma unroll
    for (int u = 0; u < 16; ++u) { accp[u] = 0.0f; acca[u] = 0.0f; }
    for (int kc = 0; kc < K; kc += 64) {
        int row = t >> 3, q = t & 7;
        {
            const float* ap = Ap + (size_t)(mt * 32 + row) * K + kc + q * 8;
            float4 f0 = *(const float4*)ap;
            float4 f1 = *(const float4*)(ap + 4);
            if (relu) {
                f0.x = fmaxf(f0.x, 0.f); f0.y = fmaxf(f0.y, 0.f);
                f0.z = fmaxf(f0.z, 0.f); f0.w = fmaxf(f0.w, 0.f);
                f1.x = fmaxf(f1.x, 0.f); f1.y = fmaxf(f1.y, 0.f);
                f1.z = fmaxf(f1.z, 0.f); f1.w = fmaxf(f1.w, 0.f);
            }
            *(float4*)&Alp[row][q * 8] = f0;
            *(float4*)&Alp[row][q * 8 + 4] = f1;
        }
        {
            const float* ap = Aa + (size_t)(mt * 32 + row) * K + kc + q * 8;
            float4 f0 = *(const float4*)ap;
            float4 f1 = *(const float4*)(ap + 4);
            for (int p = 1; p < aparts; ++p) {
                float4 g0 = *(const float4*)(ap + (size_t)p * apstride);
                float4 g1 = *(const float4*)(ap + (size_t)p * apstride + 4);
                f0.x += g0.x; f0.y += g0.y; f0.z += g0.z; f0.w += g0.w;
                f1.x += g1.x; f1.y += g1.y; f1.z += g1.z; f1.w += g1.w;
            }
            if (relu) {
                f0.x = fmaxf(f0.x, 0.f); f0.y = fmaxf(f0.y, 0.f);
                f0.z = fmaxf(f0.z, 0.f); f0.w = fmaxf(f0.w, 0.f);
                f1.x = fmaxf(f1.x, 0.f); f1.y = fmaxf(f1.y, 0.f);
                f1.z = fmaxf(f1.z, 0.f); f1.w = fmaxf(f1.w, 0.f);
            }
            *(float4*)&Ala[row][q * 8] = f0;
            *(float4*)&Ala[row][q * 8 + 4] = f1;
        }
        {
            int wrow = t >> 2, wq = t & 3;
            const float* wp = W + (size_t)(kc + wrow) * HH + wq * 32;
            #pragma unroll
            for (int u = 0; u < 32; u += 4)
                *(float4*)&Wl[wrow][wq * 32 + u] = *(const float4*)(wp + u);
        }
        __syncthreads();
        #pragma unroll 2
        for (int kk = 0; kk < 64; ++kk) {
            float a = Alp[ty][kk];
            float b2 = Ala[ty][kk];
            #pragma unroll
            for (int u = 0; u < 16; u += 4) {
                float4 wv = *(const float4*)(&Wl[kk][tx * 16 + u]);
                accp[u + 0] += a * wv.x; accp[u + 1] += a * wv.y;
                accp[u + 2] += a * wv.z; accp[u + 3] += a * wv.w;
                acca[u + 0] += b2 * wv.x; acca[u + 1] += b2 * wv.y;
                acca[u + 2] += b2 * wv.z; acca[u + 3] += b2 * wv.w;
            }
        }
        __syncthreads();
    }
    {
        float* cp = Zp + (size_t)(mt * 32 + ty) * HH + tx * 16;
        #pragma unroll
        for (int u = 0; u < 16; u += 4) {
            float4 f;
            f.x = accp[u]; f.y = accp[u + 1]; f.z = accp[u + 2]; f.w = accp[u + 3];
            *(float4*)(cp + u) = f;
        }
    }
    {
        __syncthreads();
        float* Tl = &Wl[0][0];  // reuse as [32][132]
        #pragma unroll
        for (int u = 0; u < 16; ++u) Tl[ty * 132 + tx * 16 + u] = acca[u];
        __syncthreads();
        int col = t >> 1, half = t & 1;
        unsigned short hu[16] __attribute__((aligned(16)));
        unsigned short lu[16] __attribute__((aligned(16)));
        #pragma unroll
        for (int rr = 0; rr < 16; ++rr) {
            float v = Tl[(half * 16 + rr) * 132 + col];
            unsigned short hb = f2bf(v);
            hu[rr] = hb;
            lu[rr] = f2bf(v - bf2f(hb));
        }
        size_t ob = (size_t)col * NN + mt * 32 + half * 16;
        *(uint4*)(Zthi + ob)     = *(const uint4*)&hu[0];
        *(uint4*)(Zthi + ob + 8) = *(const uint4*)&hu[8];
        *(uint4*)(Ztlo + ob)     = *(const uint4*)&lu[0];
        *(uint4*)(Ztlo + ob + 8) = *(const uint4*)&lu[8];
    }
}

// ---- D4: gemm_dual L0 (blocks 0..255) + CSR fill (blocks 256..767) ------
__global__ void __launch_bounds__(256) k_gemm_fill(
        const float* __restrict__ Ap, const float* __restrict__ Aa,
        const float* __restrict__ W, float* __restrict__ Zp,
        unsigned short* __restrict__ Zthi, unsigned short* __restrict__ Ztlo,
        int K, int relu, int aparts, int apstride,
        const int* __restrict__ ei, int* __restrict__ rowfill,
        int* __restrict__ csrcol) {
    __shared__ float Alp[32][68];
    __shared__ float Ala[32][68];
    __shared__ float Wl[64][132];
    int blk = blockIdx.x, t = threadIdx.x;
    if (blk < 256) {
        gemm_dual_body(blk, t, Ap, Aa, W, Zp, Zthi, Ztlo, K, relu, aparts, apstride,
                       Alp, Ala, Wl);
    } else {
        int e = (blk - 256) * 256 + t;
        int r = ei[e], c = ei[EE + e];
        int pos = atomicAdd(&rowfill[r], 1);
        csrcol[pos] = c;
    }
}

// plain gemm_dual for D7/D10
__global__ void __launch_bounds__(256) k_gemm_dual(
        const float* __restrict__ Ap, const float* __restrict__ Aa,
        const float* __restrict__ W, float* __restrict__ Zp,
        unsigned short* __restrict__ Zthi, unsigned short* __restrict__ Ztlo,
        int K, int relu, int aparts, int apstride) {
    __shared__ float Alp[32][68];
    __shared__ float Ala[32][68];
    __shared__ float Wl[64][132];
    gemm_dual_body(blockIdx.x, threadIdx.x, Ap, Aa, W, Zp, Zthi, Ztlo,
                   K, relu, aparts, apstride, Alp, Ala, Wl);
}

// ---- mfma body (R5-verified, pointer-based LDS) -------------------------
__device__ __forceinline__ void mfma_body(
        int blk, int t,
        const unsigned char* __restrict__ padjbits,
        const unsigned short* __restrict__ Zthi,
        const unsigned short* __restrict__ Ztlo,
        float* __restrict__ Sp, unsigned short* BhBase, unsigned short* BlBase) {
    int mt = blk >> 3, sk = blk & 7;
    int w = t >> 6, lane = t & 63;
    int quad = lane >> 4, l15 = lane & 15;
    f32x4 acc[4][8];
    #pragma unroll
    for (int m = 0; m < 4; ++m)
        #pragma unroll
        for (int i = 0; i < 8; ++i) acc[m][i] = (f32x4){0.f, 0.f, 0.f, 0.f};
    int bn = t >> 1, bq = t & 1;
    const unsigned short* zh = Zthi + (size_t)bn * NN + sk * 1024 + bq * 16;
    const unsigned short* zl = Ztlo + (size_t)bn * NN + sk * 1024 + bq * 16;
    int row0 = mt * 256 + w * 64 + l15;
    const unsigned* ab[4];
    #pragma unroll
    for (int m = 0; m < 4; ++m)
        ab[m] = (const unsigned*)(padjbits + (size_t)(row0 + m * 16) * (NN / 8)) + sk * 32;
    int ldsw = bn * 40 + bq * 16;
    int bmb = l15 * 40 + quad * 8;
    uint4 rh0, rh1, rl0, rl1;
    unsigned bits[4], nbits[4];
    rh0 = *(const uint4*)(zh + 0);
    rh1 = *(const uint4*)(zh + 8);
    rl0 = *(const uint4*)(zl + 0);
    rl1 = *(const uint4*)(zl + 8);
    #pragma unroll
    for (int m = 0; m < 4; ++m) bits[m] = ab[m][0];
    *(uint4*)(BhBase + ldsw + 0) = rh0;
    *(uint4*)(BhBase + ldsw + 8) = rh1;
    *(uint4*)(BlBase + ldsw + 0) = rl0;
    *(uint4*)(BlBase + ldsw + 8) = rl1;
    __syncthreads();
    for (int st = 0; st < 32; ++st) {
        int cur = st & 1;
        if (st < 31) {
            int k = (st + 1) * 32;
            rh0 = *(const uint4*)(zh + k);
            rh1 = *(const uint4*)(zh + k + 8);
            rl0 = *(const uint4*)(zl + k);
            rl1 = *(const uint4*)(zl + k + 8);
            #pragma unroll
            for (int m = 0; m < 4; ++m) nbits[m] = ab[m][st + 1];
        }
        short8 a[4];
        #pragma unroll
        for (int m = 0; m < 4; ++m) {
            unsigned byte = (bits[m] >> (quad * 8)) & 0xFFu;
            #pragma unroll
            for (int j = 0; j < 8; ++j)
                a[m][j] = (byte & (1u << j)) ? (short)0x3F80 : (short)0;
        }
        const unsigned short* Bh = BhBase + cur * 5120;
        const unsigned short* Bl = BlBase + cur * 5120;
        #pragma unroll
        for (int nt = 0; nt < 8; ++nt) {
            short8 fh = *(const short8*)(Bh + nt * 16 * 40 + bmb);
            short8 fl = *(const short8*)(Bl + nt * 16 * 40 + bmb);
            #pragma unroll
            for (int m = 0; m < 4; ++m) {
                acc[m][nt] = __builtin_amdgcn_mfma_f32_16x16x32_bf16(a[m], fh, acc[m][nt], 0, 0, 0);
                acc[m][nt] = __builtin_amdgcn_mfma_f32_16x16x32_bf16(a[m], fl, acc[m][nt], 0, 0, 0);
            }
        }
        if (st < 31) {
            unsigned short* BhN = BhBase + (1 - cur) * 5120;
            unsigned short* BlN = BlBase + (1 - cur) * 5120;
            *(uint4*)(BhN + ldsw + 0) = rh0;
            *(uint4*)(BhN + ldsw + 8) = rh1;
            *(uint4*)(BlN + ldsw + 0) = rl0;
            *(uint4*)(BlN + ldsw + 8) = rl1;
            #pragma unroll
            for (int m = 0; m < 4; ++m) bits[m] = nbits[m];
        }
        __syncthreads();
    }
    int dc = l15, dr = quad * 4;
    float* base = Sp + (size_t)sk * NN * HH + (size_t)(mt * 256 + w * 64 + dr) * HH;
    #pragma unroll
    for (int m = 0; m < 4; ++m)
        #pragma unroll
        for (int nt = 0; nt < 8; ++nt)
            #pragma unroll
            for (int r = 0; r < 4; ++r)
                base[(size_t)(m * 16 + r) * HH + nt * 16 + dc] = acc[m][nt][r];
}

// ---- D5: mfma L0 (blocks 0..255) + adj_write (blocks 256..8447) ---------
// LDS union: mfma Bh/Bl dbuf = 40960 B; adj cnt[8192] = 32768 B.
__global__ void __launch_bounds__(256) k_mfma_adj(
        const unsigned char* __restrict__ padjbits,
        const unsigned short* __restrict__ Zthi,
        const unsigned short* __restrict__ Ztlo,
        float* __restrict__ Sp,
        const int* __restrict__ rowptr, const int* __restrict__ csrcol,
        float* __restrict__ adj) {
    __shared__ __align__(16) char smem[40960];
    int blk = blockIdx.x, t = threadIdx.x;
    if (blk < 256) {
        mfma_body(blk, t, padjbits, Zthi, Ztlo, Sp,
                  (unsigned short*)smem, (unsigned short*)(smem + 20480));
    } else {
        int* cnt = (int*)smem;
        int row = blk - 256;
        int4 z = make_int4(0, 0, 0, 0);
        #pragma unroll
        for (int i = 0; i < 8; ++i) *(int4*)&cnt[(i * 256 + t) * 4] = z;
        __syncthreads();
        int start = rowptr[row], end = rowptr[row + 1];
        for (int e = start + t; e < end; e += 256) atomicAdd(&cnt[csrcol[e]], 1);
        __syncthreads();
        float* dst = adj + (size_t)row * NN;
        #pragma unroll
        for (int i = 0; i < 8; ++i) {
            int p = i * 1024 + t * 4;
            float4 f;
            f.x = (float)cnt[p + 0]; f.y = (float)cnt[p + 1];
            f.z = (float)cnt[p + 2]; f.w = (float)cnt[p + 3];
            *(float4*)(dst + p) = f;
        }
    }
}

// plain mfma for D9/D12
__global__ void __launch_bounds__(256) k_mfma_spmm(
        const unsigned char* __restrict__ padjbits,
        const unsigned short* __restrict__ Zthi,
        const unsigned short* __restrict__ Ztlo,
        float* __restrict__ Sp) {
    __shared__ __align__(16) char smem[40960];
    mfma_body(blockIdx.x, threadIdx.x, padjbits, Zthi, Ztlo, Sp,
              (unsigned short*)smem, (unsigned short*)(smem + 20480));
}

// ---- spmm gather (standalone, LDS-free, max occupancy) ------------------
__global__ void k_spmm_gather(const int* __restrict__ rowptr,
                              const int* __restrict__ csrcol,
                              const float* __restrict__ Z,
                              float* __restrict__ S) {
    int t = threadIdx.x;
    int row = blockIdx.x * 2 + (t >> 7);
    int col = t & 127;
    int start = rowptr[row], end = rowptr[row + 1];
    float s0 = 0.f, s1 = 0.f;
    int e = start;
    for (; e + 2 <= end; e += 2) {
        int c0 = csrcol[e], c1 = csrcol[e + 1];
        s0 += Z[(size_t)c0 * HH + col];
        s1 += Z[(size_t)c1 * HH + col];
    }
    if (e < end) s0 += Z[(size_t)csrcol[e] * HH + col];
    S[(size_t)row * HH + col] = s0 + s1;
}

// ---- D13: fused pools ---------------------------------------------------
__global__ void __launch_bounds__(256) k_pool2(const float* __restrict__ S,
                                               const float* __restrict__ Sp,
                                               const float* __restrict__ mlpW,
                                               const float* __restrict__ mlpb,
                                               float* __restrict__ pred,
                                               float* __restrict__ augp,
                                               int apstride) {
    __shared__ float ps[256], pm[256], pl[256], r0[256], r1[256];
    int aug = blockIdx.x >> 5, g = blockIdx.x & 31, t = threadIdx.x;
    const float* Sb = aug ? Sp : S;
    int parts = aug ? 8 : 1;
    float* outp = aug ? augp : pred;
    int col = t & 127, half = t >> 7;
    const float* base = Sb + (size_t)(g * CC + half * 128) * HH + col;
    float sum = 0.f, mx = -3.0e38f;
    for (int rr = 0; rr < 128; ++rr) {
        float v = base[(size_t)rr * HH];
        for (int p = 1; p < parts; ++p) v += base[(size_t)p * apstride + (size_t)rr * HH];
        v = fmaxf(v, 0.f);
        sum += v;
        mx = fmaxf(mx, v);
    }
    ps[t] = sum; pm[t] = mx;
    __syncthreads();
    if (half == 0) {
        pl[col] = (ps[col] + ps[col + 128]) * (1.0f / 256.0f);
        pl[col + 128] = fmaxf(pm[col], pm[col + 128]);
    }
    __syncthreads();
    r0[t] = pl[t] * mlpW[t * 2 + 0];
    r1[t] = pl[t] * mlpW[t * 2 + 1];
    __syncthreads();
    for (int sft = 128; sft > 0; sft >>= 1) {
        if (t < sft) { r0[t] += r0[t + sft]; r1[t] += r1[t + sft]; }
        __syncthreads();
    }
    if (t == 0) {
        float l0 = r0[0] + mlpb[0];
        float l1 = r1[0] + mlpb[1];
        outp[g * 2 + 0] = 1.0f / (1.0f + expf(-l0));
        outp[g * 2 + 1] = 1.0f / (1.0f + expf(-l1));
    }
}

extern "C" void kernel_launch(void* const* d_in, const int* in_sizes, int n_in,
                              void* d_out, int out_size, void* d_ws, size_t ws_size,
                              hipStream_t stream) {
    (void)in_sizes; (void)n_in; (void)out_size; (void)ws_size;
    const float* x     = (const float*)d_in[0];
    const int*   ei    = (const int*)d_in[1];
    const int*   gid   = (const int*)d_in[2];
    const float* pertW = (const float*)d_in[4];
    const float* pertB = (const float*)d_in[5];
    const float* maskW = (const float*)d_in[6];
    const float* w0    = (const float*)d_in[7];
    const float* w1    = (const float*)d_in[8];
    const float* w2    = (const float*)d_in[9];
    const float* mlpW  = (const float*)d_in[10];
    const float* mlpb  = (const float*)d_in[11];

    float* out  = (float*)d_out;
    float* adj  = out;
    float* padj = out + (size_t)NN * NN;
    float* Mo   = out + 2 * (size_t)NN * NN;
    float* pred = Mo + (size_t)NN * CC;
    float* augp = pred + (size_t)BBg * 2;
    float* xm   = augp + (size_t)BBg * 2;

    char* ws = (char*)d_ws;
    int*            colcnt   = (int*)ws;                            // 1MB
    int*            rowcnt   = (int*)(ws + (1 << 20));              // 32KB (contig w/ colcnt)
    int*            rowptr   = (int*)(ws + (1 << 20) + (64 << 10)); // 33KB
    int*            rowfill  = (int*)(ws + (1 << 20) + (128 << 10));// 32KB
    unsigned char*  coljs    = (unsigned char*)(ws + (2 << 20));    // 4MB
    int*            csrcol   = (int*)(ws + (6 << 20));              // 512KB
    float*          Z        = (float*)(ws + (7 << 20));            // 4MB
    float*          S        = (float*)(ws + (11 << 20));           // 4MB
    unsigned short* Zthi     = (unsigned short*)(ws + (15 << 20));  // 2MB
    unsigned short* Ztlo     = (unsigned short*)(ws + (17 << 20));  // 2MB
    float*          Sp       = (float*)(ws + (19 << 20));           // 32MB (8 partials)
    unsigned char*  padjbits = (unsigned char*)(ws + (51 << 20));   // 8MB
    const int PS = NN * HH;  // partial stride (elements)

    // D1: zero colcnt + rowcnt
    hipMemsetAsync(colcnt, 0, (1 << 20) + (32 << 10), stream);
    // D2: hist + mask
    k_hist_mask<<<2560, 256, 0, stream>>>(ei, rowcnt, colcnt, coljs,
                                          maskW, gid, x, Mo, xm);
    // D3: scan + pertadj
    k_scan_pertadj<<<1025, 256, 0, stream>>>(rowcnt, rowptr, rowfill,
                                             pertW, pertB, gid, colcnt, coljs,
                                             padj, padjbits);
    // D4: gemm_dual L0 + CSR fill
    k_gemm_fill<<<768, 256, 0, stream>>>(x, xm, w0, Z, Zthi, Ztlo, 256, 0, 1, 0,
                                         ei, rowfill, csrcol);
    // D5: mfma L0 + adj_write
    k_mfma_adj<<<256 + NN, 256, 0, stream>>>(padjbits, Zthi, Ztlo, Sp,
                                             rowptr, csrcol, adj);
    // D6: spmm L0
    k_spmm_gather<<<NN / 2, 256, 0, stream>>>(rowptr, csrcol, Z, S);
    // D7: gemm_dual L1
    k_gemm_dual<<<256, 256, 0, stream>>>(S, Sp, w1, Z, Zthi, Ztlo, 128, 1, 8, PS);
    // D8: spmm L1
    k_spmm_gather<<<NN / 2, 256, 0, stream>>>(rowptr, csrcol, Z, S);
    // D9: mfma L1
    k_mfma_spmm<<<256, 256, 0, stream>>>(padjbits, Zthi, Ztlo, Sp);
    // D10: gemm_dual L2
    k_gemm_dual<<<256, 256, 0, stream>>>(S, Sp, w2, Z, Zthi, Ztlo, 128, 1, 8, PS);
    // D11: spmm L2
    k_spmm_gather<<<NN / 2, 256, 0, stream>>>(rowptr, csrcol, Z, S);
    // D12: mfma L2
    k_mfma_spmm<<<256, 256, 0, stream>>>(padjbits, Zthi, Ztlo, Sp);
    // D13: pools
    k_pool2<<<64, 256, 0, stream>>>(S, Sp, mlpW, mlpb, pred, augp, PS);
}